// Round 1
// 653.636 us; speedup vs baseline: 1.0073x; 1.0073x over previous
//
#include <hip/hip_runtime.h>
#include <math.h>

// Problem: B=131072 rows, C=1000 classes, fp32 logits.
// out = mean(2 - 2 * softmax(x)[i, tgt[i]])  -- a single fp32 scalar.
//
// Restructure vs previous version (which was latency-serialized per row):
//  - All 16 dwordx4 loads per wave (4 rows x 4 vec4/lane) issued up-front:
//    16 KB in flight per wave, no load gated on a prior row's reduction.
//  - Target probability extracted DURING the sum pass via a per-lane
//    compare+select; cross-lane sum of that register == exp(x_t - m).
//    Removes the serial lane-0 {tgt load -> x gather} dependent chain.
//  - tgt[row] is wave-uniform -> s_load, issued at kernel entry.
//  - 4 rows' shuffle-reduce chains interleaved (independent ILP) instead
//    of 4 serial 6-deep chains.
//  - No data-dependent break: clamp + validity mask, so the fast path is
//    fully unrolled and software-pipelinable by the compiler.

constexpr int C_CLS = 1000;
constexpr int NV4 = C_CLS / 4;             // 250 float4 per row
constexpr int WAVES_PER_BLOCK = 4;         // 256 threads
constexpr int ROWS_PER_WAVE = 4;
constexpr int ROWS_PER_BLOCK = WAVES_PER_BLOCK * ROWS_PER_WAVE;  // 16

__global__ __launch_bounds__(256) void softmax_gather_kernel(
    const float* __restrict__ x, const int* __restrict__ tgt,
    float* __restrict__ partials, int B)
{
    const int lane = threadIdx.x & 63;
    const int wave = threadIdx.x >> 6;
    const int row0 = blockIdx.x * ROWS_PER_BLOCK + wave * ROWS_PER_WAVE;

    // Wave-uniform row bookkeeping + targets (s_load, issued early).
    int  rowc[ROWS_PER_WAVE];
    bool rvalid[ROWS_PER_WAVE];
    int  t[ROWS_PER_WAVE];
    #pragma unroll
    for (int r = 0; r < ROWS_PER_WAVE; ++r) {
        const int row = row0 + r;
        rvalid[r] = (row < B);
        rowc[r]   = rvalid[r] ? row : (B - 1);
        t[r]      = tgt[rowc[r]];
    }

    // ---- issue ALL row loads up-front: 16 x global_load_dwordx4 ----
    // k<3: idx = lane+64k in [0,192) < 250, always valid.
    // k==3: idx in [192,256); clamp to 249 (branchless address min), the
    //       duplicate reads are masked out of the sums below.
    float4 v[ROWS_PER_WAVE][4];
    #pragma unroll
    for (int r = 0; r < ROWS_PER_WAVE; ++r) {
        const float4* rp = reinterpret_cast<const float4*>(x + (size_t)rowc[r] * C_CLS);
        #pragma unroll
        for (int k = 0; k < 4; ++k) {
            int idx = lane + 64 * k;
            if (k == 3) idx = (idx < NV4) ? idx : (NV4 - 1);
            v[r][k] = rp[idx];
        }
    }

    // ---- per-row local max, then 4 interleaved wave-reduce chains ----
    float m[ROWS_PER_WAVE];
    #pragma unroll
    for (int r = 0; r < ROWS_PER_WAVE; ++r) {
        float mm = -INFINITY;
        #pragma unroll
        for (int k = 0; k < 4; ++k)   // dup element 249 reads are real data: max-safe
            mm = fmaxf(mm, fmaxf(fmaxf(v[r][k].x, v[r][k].y), fmaxf(v[r][k].z, v[r][k].w)));
        m[r] = mm;
    }
    #pragma unroll
    for (int off = 32; off > 0; off >>= 1) {
        #pragma unroll
        for (int r = 0; r < ROWS_PER_WAVE; ++r)
            m[r] = fmaxf(m[r], __shfl_xor(m[r], off));
    }

    // ---- exp + sum + fused target-prob extraction ----
    // k==3 validity: lane + 192 < 250  ->  lane < 58.
    const float kmask = (lane < (NV4 - 192)) ? 1.0f : 0.0f;
    float s[ROWS_PER_WAVE], te[ROWS_PER_WAVE];
    #pragma unroll
    for (int r = 0; r < ROWS_PER_WAVE; ++r) {
        float ss = 0.0f, tt = 0.0f;
        #pragma unroll
        for (int k = 0; k < 4; ++k) {
            const float w  = (k == 3) ? kmask : 1.0f;
            const int   c0 = (lane + 64 * k) * 4;   // class index of .x
            const float ex = w * __expf(v[r][k].x - m[r]);
            const float ey = w * __expf(v[r][k].y - m[r]);
            const float ez = w * __expf(v[r][k].z - m[r]);
            const float ew = w * __expf(v[r][k].w - m[r]);
            ss += (ex + ey) + (ez + ew);
            // exactly one (r, lane, k, comp) across the wave matches t[r];
            // masked lanes have c0 >= 1000 > t, so they never match.
            tt += (c0 + 0 == t[r]) ? ex : 0.0f;
            tt += (c0 + 1 == t[r]) ? ey : 0.0f;
            tt += (c0 + 2 == t[r]) ? ez : 0.0f;
            tt += (c0 + 3 == t[r]) ? ew : 0.0f;
        }
        s[r]  = ss;
        te[r] = tt;
    }
    // 8 interleaved reduce chains (s[4], te[4]).
    #pragma unroll
    for (int off = 32; off > 0; off >>= 1) {
        #pragma unroll
        for (int r = 0; r < ROWS_PER_WAVE; ++r) {
            s[r]  += __shfl_xor(s[r],  off);
            te[r] += __shfl_xor(te[r], off);
        }
    }

    float acc = 0.0f;
    #pragma unroll
    for (int r = 0; r < ROWS_PER_WAVE; ++r)
        if (rvalid[r]) acc += te[r] / s[r];   // p_target for row r

    __shared__ float sm[WAVES_PER_BLOCK];
    if (lane == 0) sm[wave] = acc;
    __syncthreads();
    if (threadIdx.x == 0) {
        float tsum = 0.0f;
        #pragma unroll
        for (int w = 0; w < WAVES_PER_BLOCK; ++w) tsum += sm[w];
        partials[blockIdx.x] = tsum;
    }
}

__global__ __launch_bounds__(1024) void finalize_kernel(
    const float* __restrict__ partials, int n, float* __restrict__ out, float invB)
{
    float s = 0.0f;
    for (int i = threadIdx.x; i < n; i += 1024) s += partials[i];
    #pragma unroll
    for (int off = 32; off > 0; off >>= 1) s += __shfl_xor(s, off);

    __shared__ float sm[16];
    const int lane = threadIdx.x & 63;
    const int wave = threadIdx.x >> 6;
    if (lane == 0) sm[wave] = s;
    __syncthreads();
    if (threadIdx.x == 0) {
        float t = 0.0f;
        #pragma unroll
        for (int w = 0; w < 16; ++w) t += sm[w];
        out[0] = 2.0f - 2.0f * t * invB;
    }
}

extern "C" void kernel_launch(void* const* d_in, const int* in_sizes, int n_in,
                              void* d_out, int out_size, void* d_ws, size_t ws_size,
                              hipStream_t stream)
{
    const float* x   = (const float*)d_in[0];
    const int*   tgt = (const int*)d_in[1];
    float*       out = (float*)d_out;
    float*       partials = (float*)d_ws;

    const int B = in_sizes[1];                                   // 131072
    const int grid = (B + ROWS_PER_BLOCK - 1) / ROWS_PER_BLOCK;  // 8192

    softmax_gather_kernel<<<grid, 256, 0, stream>>>(x, tgt, partials, B);
    finalize_kernel<<<1, 1024, 0, stream>>>(partials, grid, out, 1.0f / (float)B);
}

// Round 3
// 624.499 us; speedup vs baseline: 1.0543x; 1.0467x over previous
//
#include <hip/hip_runtime.h>
#include <math.h>

// Problem: B=131072 rows, C=1000 classes, fp32 logits.
// out = mean(2 - 2 * softmax(x)[i, tgt[i]])  -- a single fp32 scalar.
//
// Round-2 probe (fixed compile): discriminate "kernel ~320us
// (occupancy-capped)" vs "kernel ~90us (BW roofline), dur_us dominated by
// harness re-poison".
//  - ROWS_PER_WAVE 4 -> 2: data VGPRs 64 -> 32, ~7 waves/SIMD instead of
//    ~4, 2x blocks (16384) for tail/balance.
//  - Nontemporal loads on the x stream via native ext_vector_type(4)
//    (HIP float4 is a class type the builtin rejects).
//  - Target prob extracted in-pass (compare+select), no gather chain.

typedef float floatx4 __attribute__((ext_vector_type(4)));

constexpr int C_CLS = 1000;
constexpr int NV4 = C_CLS / 4;             // 250 float4 per row
constexpr int WAVES_PER_BLOCK = 4;         // 256 threads
constexpr int ROWS_PER_WAVE = 2;
constexpr int ROWS_PER_BLOCK = WAVES_PER_BLOCK * ROWS_PER_WAVE;  // 8

__global__ __launch_bounds__(256) void softmax_gather_kernel(
    const float* __restrict__ x, const int* __restrict__ tgt,
    float* __restrict__ partials, int B)
{
    const int lane = threadIdx.x & 63;
    const int wave = threadIdx.x >> 6;
    const int row0 = blockIdx.x * ROWS_PER_BLOCK + wave * ROWS_PER_WAVE;

    // Wave-uniform row bookkeeping + targets (issued early).
    int  rowc[ROWS_PER_WAVE];
    bool rvalid[ROWS_PER_WAVE];
    int  t[ROWS_PER_WAVE];
    #pragma unroll
    for (int r = 0; r < ROWS_PER_WAVE; ++r) {
        const int row = row0 + r;
        rvalid[r] = (row < B);
        rowc[r]   = rvalid[r] ? row : (B - 1);
        t[r]      = tgt[rowc[r]];
    }

    // ---- issue ALL row loads up-front: 8 x global_load_dwordx4 (nt) ----
    // k<3: idx = lane+64k in [0,192) < 250, always valid.
    // k==3: idx in [192,256); clamp to 249, duplicates masked out below.
    floatx4 v[ROWS_PER_WAVE][4];
    #pragma unroll
    for (int r = 0; r < ROWS_PER_WAVE; ++r) {
        const floatx4* rp = reinterpret_cast<const floatx4*>(x + (size_t)rowc[r] * C_CLS);
        #pragma unroll
        for (int k = 0; k < 4; ++k) {
            int idx = lane + 64 * k;
            if (k == 3) idx = (idx < NV4) ? idx : (NV4 - 1);
            v[r][k] = __builtin_nontemporal_load(&rp[idx]);
        }
    }

    // ---- per-row local max, then interleaved wave-reduce chains ----
    float m[ROWS_PER_WAVE];
    #pragma unroll
    for (int r = 0; r < ROWS_PER_WAVE; ++r) {
        float mm = -INFINITY;
        #pragma unroll
        for (int k = 0; k < 4; ++k)   // dup element-249 reads are real data: max-safe
            mm = fmaxf(mm, fmaxf(fmaxf(v[r][k].x, v[r][k].y), fmaxf(v[r][k].z, v[r][k].w)));
        m[r] = mm;
    }
    #pragma unroll
    for (int off = 32; off > 0; off >>= 1) {
        #pragma unroll
        for (int r = 0; r < ROWS_PER_WAVE; ++r)
            m[r] = fmaxf(m[r], __shfl_xor(m[r], off));
    }

    // ---- exp + sum + fused target-prob extraction ----
    // k==3 validity: lane + 192 < 250  ->  lane < 58.
    const float kmask = (lane < (NV4 - 192)) ? 1.0f : 0.0f;
    float s[ROWS_PER_WAVE], te[ROWS_PER_WAVE];
    #pragma unroll
    for (int r = 0; r < ROWS_PER_WAVE; ++r) {
        float ss = 0.0f, tt = 0.0f;
        #pragma unroll
        for (int k = 0; k < 4; ++k) {
            const float w  = (k == 3) ? kmask : 1.0f;
            const int   c0 = (lane + 64 * k) * 4;   // class index of .x
            const float ex = w * __expf(v[r][k].x - m[r]);
            const float ey = w * __expf(v[r][k].y - m[r]);
            const float ez = w * __expf(v[r][k].z - m[r]);
            const float ew = w * __expf(v[r][k].w - m[r]);
            ss += (ex + ey) + (ez + ew);
            // exactly one (lane,k,comp) across the wave matches t[r];
            // masked lanes have c0 >= 1000 > t, so they never match.
            tt += (c0 + 0 == t[r]) ? ex : 0.0f;
            tt += (c0 + 1 == t[r]) ? ey : 0.0f;
            tt += (c0 + 2 == t[r]) ? ez : 0.0f;
            tt += (c0 + 3 == t[r]) ? ew : 0.0f;
        }
        s[r]  = ss;
        te[r] = tt;
    }
    #pragma unroll
    for (int off = 32; off > 0; off >>= 1) {
        #pragma unroll
        for (int r = 0; r < ROWS_PER_WAVE; ++r) {
            s[r]  += __shfl_xor(s[r],  off);
            te[r] += __shfl_xor(te[r], off);
        }
    }

    float acc = 0.0f;
    #pragma unroll
    for (int r = 0; r < ROWS_PER_WAVE; ++r)
        if (rvalid[r]) acc += te[r] / s[r];   // p_target for row r

    __shared__ float sm[WAVES_PER_BLOCK];
    if (lane == 0) sm[wave] = acc;
    __syncthreads();
    if (threadIdx.x == 0) {
        float tsum = 0.0f;
        #pragma unroll
        for (int w = 0; w < WAVES_PER_BLOCK; ++w) tsum += sm[w];
        partials[blockIdx.x] = tsum;
    }
}

__global__ __launch_bounds__(1024) void finalize_kernel(
    const float* __restrict__ partials, int n, float* __restrict__ out, float invB)
{
    float s = 0.0f;
    for (int i = threadIdx.x; i < n; i += 1024) s += partials[i];
    #pragma unroll
    for (int off = 32; off > 0; off >>= 1) s += __shfl_xor(s, off);

    __shared__ float sm[16];
    const int lane = threadIdx.x & 63;
    const int wave = threadIdx.x >> 6;
    if (lane == 0) sm[wave] = s;
    __syncthreads();
    if (threadIdx.x == 0) {
        float t = 0.0f;
        #pragma unroll
        for (int w = 0; w < 16; ++w) t += sm[w];
        out[0] = 2.0f - 2.0f * t * invB;
    }
}

extern "C" void kernel_launch(void* const* d_in, const int* in_sizes, int n_in,
                              void* d_out, int out_size, void* d_ws, size_t ws_size,
                              hipStream_t stream)
{
    const float* x   = (const float*)d_in[0];
    const int*   tgt = (const int*)d_in[1];
    float*       out = (float*)d_out;
    float*       partials = (float*)d_ws;

    const int B = in_sizes[1];                                   // 131072
    const int grid = (B + ROWS_PER_BLOCK - 1) / ROWS_PER_BLOCK;  // 16384

    softmax_gather_kernel<<<grid, 256, 0, stream>>>(x, tgt, partials, B);
    finalize_kernel<<<1, 1024, 0, stream>>>(partials, grid, out, 1.0f / (float)B);
}